// Round 5
// baseline (3501.749 us; speedup 1.0000x reference)
//
#include <hip/hip_runtime.h>
#include <float.h>

#define NLVL 12
#define NB   16
#define TPB  1024
#define GRID 256          // 1 block/CU, cooperative
#define NGRP 8
#define GRPSZ (GRID / NGRP)

// meta: [0..16) cf | [16..32) cb | [32..48) co | [48..64) curf | [64..80) curb |
//       [80..96) curo | [96..109) basef | [128..141) baseb | [160..177) baseo
// bar:  [g*32] group counters g<8 | [256] root | [272] release epoch

struct Params {
    const int *nt, *ninv, *src, *dst, *fl, *bl, *batch;
    const float *We, *be, *Wf, *bf, *Wb, *bb;
    float *h, *hN, *out;
    int *rowptr, *cursor, *col, *nb_f, *nb_b, *onodes, *bsums, *meta, *plarr, *bar;
    int N, E, M, outN;
};

__device__ __forceinline__ void gbar(int* bar, int& epoch) {
    __threadfence();
    __syncthreads();
    if (threadIdx.x == 0) {
        int g = blockIdx.x & (NGRP - 1);
        int pos = __hip_atomic_fetch_add(&bar[g * 32], 1, __ATOMIC_ACQ_REL, __HIP_MEMORY_SCOPE_AGENT);
        if (pos == GRPSZ - 1) {
            __hip_atomic_store(&bar[g * 32], 0, __ATOMIC_RELAXED, __HIP_MEMORY_SCOPE_AGENT);
            int r = __hip_atomic_fetch_add(&bar[256], 1, __ATOMIC_ACQ_REL, __HIP_MEMORY_SCOPE_AGENT);
            if (r == NGRP - 1) {
                __hip_atomic_store(&bar[256], 0, __ATOMIC_RELAXED, __HIP_MEMORY_SCOPE_AGENT);
                __hip_atomic_store(&bar[272], epoch, __ATOMIC_RELEASE, __HIP_MEMORY_SCOPE_AGENT);
            }
        }
        while (__hip_atomic_load(&bar[272], __ATOMIC_ACQUIRE, __HIP_MEMORY_SCOPE_AGENT) < epoch)
            __builtin_amdgcn_s_sleep(4);
        __threadfence();
    }
    __syncthreads();
    epoch++;
}

__device__ inline void atomicMaxF(float* addr, float val) {
    int* ai = (int*)addr;
    int old = *ai;
    while (__int_as_float(old) < val) {
        int assumed = old;
        old = atomicCAS(ai, assumed, __float_as_int(val));
        if (old == assumed) break;
    }
}

__global__ __launch_bounds__(TPB, 4) void k_mega(Params p) {
    __shared__ float Ws[64 * 64];
    __shared__ int   si[TPB];
    __shared__ int   hf[NLVL], hb[NLVL], ho[NB], basef[NLVL], baseb[NLVL], baseo[NB];

    const int tid = threadIdx.x, bid = blockIdx.x;
    const int gtid = bid * TPB + tid, gs = GRID * TPB;
    const int lane = tid & 63;
    const int wid = gtid >> 6, nw = gs >> 6;       // 4096 waves
    const int N = p.N, E = p.E, M = p.M;
    int ep = 1;

    // ---------- P0: zero rowptr/meta, init out ----------
    for (int i = gtid; i < M + 1; i += gs) p.rowptr[i] = 0;
    for (int i = gtid; i < 48; i += gs) p.meta[i] = 0;
    for (int i = gtid; i < p.outN; i += gs)
        p.out[i] = ((i & 127) < 64) ? -FLT_MAX : 0.0f;
    gbar(p.bar, ep);

    // ---------- P1: degrees + hist + plarr + encoder ----------
    for (int e = gtid; e < E; e += gs) {
        atomicAdd(&p.rowptr[p.dst[e]], 1);
        atomicAdd(&p.rowptr[N + p.src[e]], 1);
    }
    if (tid < NLVL) { hf[tid] = 0; hb[tid] = 0; }
    if (tid < NB) ho[tid] = 0;
    __syncthreads();
    for (int i = gtid; i < N; i += gs) {
        int f = p.fl[i], b = p.bl[i];
        p.plarr[i] = f | (b << 4);
        atomicAdd(&hf[f], 1);
        atomicAdd(&hb[b], 1);
        if (p.nt[i] == 1) atomicAdd(&ho[p.batch[i]], 1);
    }
    __syncthreads();
    if (tid < NLVL) { atomicAdd(&p.meta[tid], hf[tid]); atomicAdd(&p.meta[16 + tid], hb[tid]); }
    if (tid < NB) atomicAdd(&p.meta[32 + tid], ho[tid]);
    for (int t = gtid; t < N * 16; t += gs) {
        int v = t >> 4;
        int j = (t & 15) * 4;
        float a = (float)p.nt[v], c = (float)p.ninv[v];
        float4 w0 = *(const float4*)(p.We + j);
        float4 w1 = *(const float4*)(p.We + 64 + j);
        float4 b  = *(const float4*)(p.be + j);
        float4 r;
        r.x = fmaf(a, w0.x, fmaf(c, w1.x, b.x));
        r.y = fmaf(a, w0.y, fmaf(c, w1.y, b.y));
        r.z = fmaf(a, w0.z, fmaf(c, w1.z, b.z));
        r.w = fmaf(a, w0.w, fmaf(c, w1.w, b.w));
        *(float4*)(p.h + (size_t)v * 64 + j) = r;
    }
    gbar(p.bar, ep);

    // ---------- P2a: per-block chunk sums of rowptr[0..M) ----------
    const int chunk = (M + GRID - 1) / GRID;
    const int per = (chunk + TPB - 1) / TPB;
    const int c0 = bid * chunk;
    int tsum = 0;
    for (int k = 0; k < per; k++) {
        int idx = c0 + tid * per + k;
        if (idx < c0 + chunk && idx < M) tsum += p.rowptr[idx];
    }
    si[tid] = tsum;
    __syncthreads();
    for (int off = TPB / 2; off > 0; off >>= 1) {
        if (tid < off) si[tid] += si[tid + off];
        __syncthreads();
    }
    if (tid == 0) p.bsums[bid] = si[0];
    gbar(p.bar, ep);

    // ---------- P2b: block 0 scans bsums; block 1 scans meta ----------
    if (bid == 0) {
        int v = (tid < GRID) ? p.bsums[tid] : 0;
        si[tid] = v;
        __syncthreads();
        for (int off = 1; off < TPB; off <<= 1) {
            int a = (tid >= off) ? si[tid - off] : 0;
            __syncthreads();
            si[tid] += a;
            __syncthreads();
        }
        if (tid < GRID) p.bsums[tid] = si[tid] - v;
    } else if (bid == 1) {
        if (tid == 0) { int s = 0; for (int l = 0; l < NLVL; l++) { p.meta[96 + l] = s; p.meta[48 + l] = s; s += p.meta[l]; } p.meta[96 + NLVL] = s; }
        if (tid == 1) { int s = 0; for (int l = 0; l < NLVL; l++) { p.meta[128 + l] = s; p.meta[64 + l] = s; s += p.meta[16 + l]; } p.meta[128 + NLVL] = s; }
        if (tid == 2) { int s = 0; for (int b = 0; b < NB; b++) { p.meta[160 + b] = s; p.meta[80 + b] = s; s += p.meta[32 + b]; } p.meta[160 + NB] = s; }
    }
    gbar(p.bar, ep);

    // ---------- P2c: finalize rowptr/cursor ----------
    {
        int off0 = p.bsums[bid];
        si[tid] = tsum;
        __syncthreads();
        for (int off = 1; off < TPB; off <<= 1) {
            int a = (tid >= off) ? si[tid - off] : 0;
            __syncthreads();
            si[tid] += a;
            __syncthreads();
        }
        int run = off0 + si[tid] - tsum;
        for (int k = 0; k < per; k++) {
            int idx = c0 + tid * per + k;
            if (idx < c0 + chunk && idx < M) {
                int c = p.rowptr[idx];
                p.rowptr[idx] = run;
                p.cursor[idx] = run;
                run += c;
            }
        }
        if (gtid == 0) p.rowptr[M] = 2 * E;
    }
    gbar(p.bar, ep);

    // ---------- P3: CSR fill (packed) + node scatter (packed) ----------
    for (int e = gtid; e < E; e += gs) {
        int s = p.src[e], d = p.dst[e];
        int ps = p.plarr[s], pd = p.plarr[d];
        p.col[atomicAdd(&p.cursor[d], 1)] = s | (ps << 18);      // in-edge: other = src
        p.col[atomicAdd(&p.cursor[N + s], 1)] = d | (pd << 18);  // out-edge: other = dst
    }
    for (int i0 = bid * TPB; i0 < N; i0 += gs) {
        int i = i0 + tid;
        bool valid = (i < N);
        if (tid < NLVL) { hf[tid] = 0; hb[tid] = 0; }
        if (tid < NB) ho[tid] = 0;
        __syncthreads();
        int lf = 0, lb = 0, ob = -1, pl = 0;
        if (valid) {
            lf = p.fl[i]; lb = p.bl[i];
            pl = lf | (lb << 4);
            atomicAdd(&hf[lf], 1);
            atomicAdd(&hb[lb], 1);
            if (p.nt[i] == 1) { ob = p.batch[i]; atomicAdd(&ho[ob], 1); }
        }
        __syncthreads();
        if (tid < NLVL) {
            basef[tid] = atomicAdd(&p.meta[48 + tid], hf[tid]);
            baseb[tid] = atomicAdd(&p.meta[64 + tid], hb[tid]);
            hf[tid] = 0; hb[tid] = 0;
        }
        if (tid < NB) {
            baseo[tid] = atomicAdd(&p.meta[80 + tid], ho[tid]);
            ho[tid] = 0;
        }
        __syncthreads();
        if (valid) {
            int pk = i | (pl << 18);
            p.nb_f[basef[lf] + atomicAdd(&hf[lf], 1)] = pk;
            p.nb_b[baseb[lb] + atomicAdd(&hb[lb], 1)] = pk;
            if (ob >= 0) p.onodes[baseo[ob] + atomicAdd(&ho[ob], 1)] = pk;
        }
        __syncthreads();
    }
    gbar(p.bar, ep);

    // ---------- sweeps: buffer-parity, one barrier per level ----------
    const int q  = lane >> 4;
    const int fb = (lane & 15) * 4;
    for (int dir = 0; dir < 2; dir++) {
        const int* nb     = dir ? p.nb_b : p.nb_f;
        const int* base   = p.meta + (dir ? 128 : 96);
        const int* rp     = p.rowptr + (dir ? N : 0);
        const float* W    = dir ? p.Wb : p.Wf;
        const float* bias = dir ? p.bb : p.bf;
        for (int j = tid; j < 4096; j += TPB) Ws[j] = W[j];
        __syncthreads();
        float bv = bias[lane];
        for (int l = 1; l < NLVL; l++) {
            int start = base[l], cnt = base[l + 1] - start;
            for (int i = wid; i < cnt; i += nw) {
                int e = nb[start + i];
                int v = e & 0x3FFFF;
                int flv = (e >> 18) & 15;
                int rpv = rp[v], rpe = rp[v + 1];
                int deg = rpe - rpv;
                float4 acc = make_float4(0.f, 0.f, 0.f, 0.f);
                for (int cb = rpv + q; cb < rpe; cb += 4) {
                    int cu = p.col[cb];
                    int u = cu & 0x3FFFF;
                    int flu = (cu >> 18) & 15;
                    int blu = (cu >> 22) & 15;
                    bool useN;
                    if (dir == 0) useN = (flu > 0) && (flu < l);
                    else          useN = ((flu > 0) != ((blu > 0) && (blu < l)));
                    const float* sb = useN ? p.hN : p.h;
                    const float4 x = *(const float4*)(sb + (size_t)u * 64 + fb);
                    acc.x += x.x; acc.y += x.y; acc.z += x.z; acc.w += x.w;
                }
                acc.x += __shfl_xor(acc.x, 16, 64); acc.y += __shfl_xor(acc.y, 16, 64);
                acc.z += __shfl_xor(acc.z, 16, 64); acc.w += __shfl_xor(acc.w, 16, 64);
                acc.x += __shfl_xor(acc.x, 32, 64); acc.y += __shfl_xor(acc.y, 32, 64);
                acc.z += __shfl_xor(acc.z, 32, 64); acc.w += __shfl_xor(acc.w, 32, 64);
                float o = bv * (float)deg;
                #pragma unroll
                for (int j = 0; j < 16; j++) {
                    float ax = __shfl(acc.x, j, 64);
                    float ay = __shfl(acc.y, j, 64);
                    float az = __shfl(acc.z, j, 64);
                    float aw = __shfl(acc.w, j, 64);
                    o = fmaf(ax, Ws[(4 * j + 0) * 64 + lane], o);
                    o = fmaf(ay, Ws[(4 * j + 1) * 64 + lane], o);
                    o = fmaf(az, Ws[(4 * j + 2) * 64 + lane], o);
                    o = fmaf(aw, Ws[(4 * j + 3) * 64 + lane], o);
                }
                float* db = (dir == 0) ? p.hN : ((flv > 0) ? p.h : p.hN);
                db[(size_t)v * 64 + lane] = o;
            }
            gbar(p.bar, ep);
        }
    }

    // ---------- readout (4096 waves, 256 slices per batch) ----------
    {
        const int S = (GRID * TPB / 64) / NB;     // 256
        int b = wid / S;
        int sl = wid % S;
        int a0 = p.meta[160 + b], a1 = p.meta[160 + b + 1];
        int cnt = a1 - a0;
        if (cnt > 0) {
            int lo = a0 + (int)(((long long)cnt * sl) / S);
            int hi = a0 + (int)(((long long)cnt * (sl + 1)) / S);
            if (hi > lo) {
                float mx = -FLT_MAX, sm = 0.f;
                for (int k = lo; k < hi; k += 64) {
                    int take = hi - k; if (take > 64) take = 64;
                    int el = (lane < take) ? p.onodes[k + lane] : 0;
                    for (int j = 0; j < take; j++) {
                        int e = __shfl(el, j, 64);
                        int v = e & 0x3FFFF;
                        int flv = (e >> 18) & 15, blv = (e >> 22) & 15;
                        const float* sb = ((flv > 0) != (blv > 0)) ? p.hN : p.h;
                        float x = sb[(size_t)v * 64 + lane];
                        mx = fmaxf(mx, x);
                        sm += x;
                    }
                }
                atomicMaxF(&p.out[b * 128 + lane], mx);
                atomicAdd(&p.out[b * 128 + 64 + lane], sm);
            }
        }
    }
}

extern "C" void kernel_launch(void* const* d_in, const int* in_sizes, int n_in,
                              void* d_out, int out_size, void* d_ws, size_t ws_size,
                              hipStream_t stream) {
    int N = in_sizes[0];
    int E = in_sizes[2] / 2;
    int M = 2 * N;

    Params p;
    p.nt    = (const int*)d_in[0];
    p.ninv  = (const int*)d_in[1];
    p.src   = (const int*)d_in[2];
    p.dst   = (const int*)d_in[2] + E;
    p.fl    = (const int*)d_in[3];
    p.bl    = (const int*)d_in[4];
    p.batch = (const int*)d_in[5];
    p.We    = (const float*)d_in[6];
    p.be    = (const float*)d_in[7];
    p.Wf    = (const float*)d_in[8];
    p.bf    = (const float*)d_in[9];
    p.Wb    = (const float*)d_in[10];
    p.bb    = (const float*)d_in[11];
    p.out   = (float*)d_out;
    p.N = N; p.E = E; p.M = M; p.outN = out_size;

    char* ws = (char*)d_ws;
    size_t off = 0;
    auto alloc = [&](size_t bytes) -> char* {
        char* q = ws + off;
        off = (off + bytes + 255) & ~(size_t)255;
        return q;
    };
    p.h      = (float*)alloc((size_t)N * 64 * sizeof(float));
    p.hN     = (float*)alloc((size_t)N * 64 * sizeof(float));
    p.rowptr = (int*)  alloc((size_t)(M + 1) * sizeof(int));
    p.cursor = (int*)  alloc((size_t)M * sizeof(int));
    p.col    = (int*)  alloc((size_t)2 * E * sizeof(int));
    p.nb_f   = (int*)  alloc((size_t)N * sizeof(int));
    p.nb_b   = (int*)  alloc((size_t)N * sizeof(int));
    p.onodes = (int*)  alloc((size_t)N * sizeof(int));
    p.plarr  = (int*)  alloc((size_t)N * sizeof(int));
    p.bsums  = (int*)  alloc(1024 * sizeof(int));
    p.meta   = (int*)  alloc(256 * sizeof(int));
    p.bar    = (int*)  alloc(2048);

    hipMemsetAsync(p.bar, 0, 2048, stream);   // barrier counters + release epoch

    void* args[] = { &p };
    hipLaunchCooperativeKernel((void*)k_mega, dim3(GRID), dim3(TPB), args, 0, stream);
}